// Round 20
// baseline (635.986 us; speedup 1.0000x reference)
//
#include <hip/hip_runtime.h>
#include <hip/hip_bf16.h>

#define B_ 2
#define S_ 1024
#define D_ 1024
#define H_ 16
#define HD_ 64
#define FF_ 4096
#define NROW_ (B_*S_)

typedef __hip_bfloat16 bf16;
typedef float f32x4 __attribute__((ext_vector_type(4)));
typedef int int4v __attribute__((ext_vector_type(4)));
typedef __bf16 bf16x8 __attribute__((ext_vector_type(8)));

__device__ __forceinline__ float bf2f(unsigned short u){
  return __uint_as_float((unsigned)u << 16);
}
__device__ __forceinline__ unsigned short f2bf(float f){
  unsigned u = __float_as_uint(f);
  return (unsigned short)((u + 0x7FFFu + ((u >> 16) & 1u)) >> 16);
}
__device__ __forceinline__ float gelu_gate(float a, float g){
  float t = tanhf(0.7978845608f * g * (1.f + 0.044715f * g * g));
  return a * 0.5f * g * (1.f + t);
}
// bijective XCD swizzle — ONLY for mstats/mpv (round-15 lesson).
__device__ __forceinline__ void xcd_swz(int& bx, int& by){
  int nx = gridDim.x, tot = nx * gridDim.y;
  int flat = by * nx + bx;
  int cpx = tot >> 3;
  int w = (flat & 7) * cpx + (flat >> 3);
  bx = w % nx; by = w / nx;
}

// ============================================================================
// ===========================  FAST PATH (MFMA)  =============================
// ============================================================================

// ---- fused transpose+convert for all 7 weights: f32 [K][N] -> bf16 [N][K] ----
__global__ __launch_bounds__(256) void tcvt_all(
    const float* __restrict__ w_qkv1, const float* __restrict__ w_qkv2,
    const float* __restrict__ w_o1,   const float* __restrict__ w_o2,
    const float* __restrict__ w1,     const float* __restrict__ wg,
    const float* __restrict__ w2,
    unsigned short* __restrict__ t_qkv1, unsigned short* __restrict__ t_qkv2,
    unsigned short* __restrict__ t_o1,   unsigned short* __restrict__ t_o2,
    unsigned short* __restrict__ t_w1,   unsigned short* __restrict__ t_wg,
    unsigned short* __restrict__ t_w2){
  __shared__ float tile[32][33];
  int id = blockIdx.x;
  const float* W; unsigned short* Wt; int K, N, t0;
  if      (id <  3072){ W=w_qkv1; Wt=t_qkv1; K=1024; N=3072; t0=0; }
  else if (id <  6144){ W=w_qkv2; Wt=t_qkv2; K=1024; N=3072; t0=3072; }
  else if (id <  7168){ W=w_o1;   Wt=t_o1;   K=1024; N=1024; t0=6144; }
  else if (id <  8192){ W=w_o2;   Wt=t_o2;   K=1024; N=1024; t0=7168; }
  else if (id < 12288){ W=w1;     Wt=t_w1;   K=1024; N=4096; t0=8192; }
  else if (id < 45056){ W=wg;     Wt=t_wg;   K=4096; N=8192; t0=12288; }
  else               { W=w2;     Wt=t_w2;   K=4096; N=1024; t0=45056; }
  int tl = id - t0;
  int nx = N >> 5;
  int n0 = (tl % nx) * 32, k0 = (tl / nx) * 32;
  const int t = threadIdx.x;
  #pragma unroll
  for (int i = 0; i < 4; i++){
    int idx = t + i*256; int r = idx>>5, c = idx&31;
    tile[r][c] = W[(size_t)(k0+r)*N + n0 + c];
  }
  __syncthreads();
  #pragma unroll
  for (int i = 0; i < 4; i++){
    int idx = t + i*256; int r = idx>>5, c = idx&31;
    Wt[(size_t)(n0+r)*K + k0 + c] = f2bf(tile[c][r]);
  }
}

// ---- LayerNorm: f32 in -> bf16 out ----
__global__ __launch_bounds__(256) void lnb_k(const float* __restrict__ x,
    const float* __restrict__ sc, const float* __restrict__ bi, unsigned short* __restrict__ y){
  const int row = blockIdx.x;
  const int t = threadIdx.x;
  const float* xr = x + (size_t)row * D_;
  float4 v = *(const float4*)&xr[t*4];
  __shared__ float red[8];
  float sum = v.x + v.y + v.z + v.w;
  #pragma unroll
  for (int o = 32; o > 0; o >>= 1) sum += __shfl_down(sum, o);
  if ((t & 63) == 0) red[t >> 6] = sum;
  __syncthreads();
  if (t == 0) red[4] = (red[0]+red[1]+red[2]+red[3]) * (1.f / D_);
  __syncthreads();
  const float mean = red[4];
  const float dx = v.x-mean, dy = v.y-mean, dz = v.z-mean, dw = v.w-mean;
  float sq = dx*dx + dy*dy + dz*dz + dw*dw;
  #pragma unroll
  for (int o = 32; o > 0; o >>= 1) sq += __shfl_down(sq, o);
  if ((t & 63) == 0) red[t >> 6] = sq;
  __syncthreads();
  if (t == 0) red[5] = (red[0]+red[1]+red[2]+red[3]) * (1.f / D_);
  __syncthreads();
  const float rstd = rsqrtf(red[5] + 1e-6f);
  float4 s4 = *(const float4*)&sc[t*4];
  float4 b4 = *(const float4*)&bi[t*4];
  ushort4 ov;
  ov.x = f2bf(dx*rstd*s4.x + b4.x);
  ov.y = f2bf(dy*rstd*s4.y + b4.y);
  ov.z = f2bf(dz*rstd*s4.z + b4.z);
  ov.w = f2bf(dw*rstd*s4.w + b4.w);
  *(ushort4*)&y[(size_t)row*D_ + t*4] = ov;
}

// ---- MFMA GEMM, BK=64, BN=128 (for N>=2048 shapes) ----
template<bool HAS_RES, bool RES_BF16, bool OUT_BF16>
__global__ __launch_bounds__(256) void mgemm(const unsigned short* __restrict__ A,
    const unsigned short* __restrict__ Bt, const float* __restrict__ bias,
    const void* __restrict__ res, void* __restrict__ Cv, int M, int N, int K){
  __shared__ unsigned short As[2][128*32];
  __shared__ unsigned short Bs[2][128*32];
  const int tid = threadIdx.x;
  const int bm = blockIdx.y*128, bn = blockIdx.x*128;
  const int lane = tid & 63, lq = lane >> 4, lr = lane & 15;
  const int wv = tid >> 6, wr = wv >> 1, wc = wv & 1;
  f32x4 acc[4][4] = {};
  int4v ra[2][2], rb[2][2];
  #pragma unroll
  for (int hh = 0; hh < 2; hh++)
    #pragma unroll
    for (int i = 0; i < 2; i++){
      int f = tid + i*256; int row = f>>2, s = f&3;
      ra[hh][i] = *(const int4v*)&A[(size_t)(bm+row)*K + hh*32 + s*8];
      rb[hh][i] = *(const int4v*)&Bt[(size_t)(bn+row)*K + hh*32 + s*8];
    }
  for (int k0 = 0; k0 < K; k0 += 64){
    __syncthreads();
    #pragma unroll
    for (int hh = 0; hh < 2; hh++)
      #pragma unroll
      for (int i = 0; i < 2; i++){
        int f = tid + i*256; int row = f>>2, s = f&3;
        int off = row*32 + ((s + (row>>1))&3)*8;
        *(int4v*)&As[hh][off] = ra[hh][i];
        *(int4v*)&Bs[hh][off] = rb[hh][i];
      }
    __syncthreads();
    if (k0 + 64 < K){
      #pragma unroll
      for (int hh = 0; hh < 2; hh++){
        int kn = k0 + 64 + hh*32;
        #pragma unroll
        for (int i = 0; i < 2; i++){
          int f = tid + i*256; int row = f>>2, s = f&3;
          ra[hh][i] = *(const int4v*)&A[(size_t)(bm+row)*K + kn + s*8];
          rb[hh][i] = *(const int4v*)&Bt[(size_t)(bn+row)*K + kn + s*8];
        }
      }
    }
    #pragma unroll
    for (int hh = 0; hh < 2; hh++){
      bf16x8 af[4], bfr[4];
      #pragma unroll
      for (int fm = 0; fm < 4; fm++){
        int r = wr*64 + fm*16 + lr;
        af[fm] = *(const bf16x8*)&As[hh][r*32 + ((lq + (r>>1))&3)*8];
      }
      #pragma unroll
      for (int fn = 0; fn < 4; fn++){
        int r = wc*64 + fn*16 + lr;
        bfr[fn] = *(const bf16x8*)&Bs[hh][r*32 + ((lq + (r>>1))&3)*8];
      }
      #pragma unroll
      for (int fm = 0; fm < 4; fm++)
        #pragma unroll
        for (int fn = 0; fn < 4; fn++)
          acc[fm][fn] = __builtin_amdgcn_mfma_f32_16x16x32_bf16(af[fm], bfr[fn], acc[fm][fn], 0, 0, 0);
    }
  }
  #pragma unroll
  for (int fm = 0; fm < 4; fm++)
    #pragma unroll
    for (int fn = 0; fn < 4; fn++)
      #pragma unroll
      for (int rr = 0; rr < 4; rr++){
        int r = bm + wr*64 + fm*16 + lq*4 + rr;
        int c = bn + wc*64 + fn*16 + lr;
        size_t o = (size_t)r*N + c;
        float v = acc[fm][fn][rr] + bias[c];
        if (HAS_RES){
          if (RES_BF16) v += bf2f(((const unsigned short*)res)[o]);
          else          v += ((const float*)res)[o];
        }
        if (OUT_BF16) ((unsigned short*)Cv)[o] = f2bf(v);
        else          ((float*)Cv)[o] = v;
      }
}

// ---- MFMA GEMM, BK=64, BN=64 (for N=1024 shapes: grid (16,16)=256 blocks) ----
template<bool HAS_RES, bool RES_BF16, bool OUT_BF16>
__global__ __launch_bounds__(256) void mgemm64(const unsigned short* __restrict__ A,
    const unsigned short* __restrict__ Bt, const float* __restrict__ bias,
    const void* __restrict__ res, void* __restrict__ Cv, int M, int N, int K){
  __shared__ unsigned short As[2][128*32];
  __shared__ unsigned short Bs[2][64*32];
  const int tid = threadIdx.x;
  const int bm = blockIdx.y*128, bn = blockIdx.x*64;
  const int lane = tid & 63, lq = lane >> 4, lr = lane & 15;
  const int wv = tid >> 6, wr = wv >> 1, wc = wv & 1;
  f32x4 acc[4][2] = {};
  int4v ra[2][2], rb[2];
  #pragma unroll
  for (int hh = 0; hh < 2; hh++){
    #pragma unroll
    for (int i = 0; i < 2; i++){
      int f = tid + i*256; int row = f>>2, s = f&3;
      ra[hh][i] = *(const int4v*)&A[(size_t)(bm+row)*K + hh*32 + s*8];
    }
    { int row = tid>>2, s = tid&3;
      rb[hh] = *(const int4v*)&Bt[(size_t)(bn+row)*K + hh*32 + s*8];
    }
  }
  for (int k0 = 0; k0 < K; k0 += 64){
    __syncthreads();
    #pragma unroll
    for (int hh = 0; hh < 2; hh++){
      #pragma unroll
      for (int i = 0; i < 2; i++){
        int f = tid + i*256; int row = f>>2, s = f&3;
        *(int4v*)&As[hh][row*32 + ((s + (row>>1))&3)*8] = ra[hh][i];
      }
      { int row = tid>>2, s = tid&3;
        *(int4v*)&Bs[hh][row*32 + ((s + (row>>1))&3)*8] = rb[hh];
      }
    }
    __syncthreads();
    if (k0 + 64 < K){
      #pragma unroll
      for (int hh = 0; hh < 2; hh++){
        int kn = k0 + 64 + hh*32;
        #pragma unroll
        for (int i = 0; i < 2; i++){
          int f = tid + i*256; int row = f>>2, s = f&3;
          ra[hh][i] = *(const int4v*)&A[(size_t)(bm+row)*K + kn + s*8];
        }
        { int row = tid>>2, s = tid&3;
          rb[hh] = *(const int4v*)&Bt[(size_t)(bn+row)*K + kn + s*8];
        }
      }
    }
    #pragma unroll
    for (int hh = 0; hh < 2; hh++){
      bf16x8 af[4], bfr[2];
      #pragma unroll
      for (int fm = 0; fm < 4; fm++){
        int r = wr*64 + fm*16 + lr;
        af[fm] = *(const bf16x8*)&As[hh][r*32 + ((lq + (r>>1))&3)*8];
      }
      #pragma unroll
      for (int fn = 0; fn < 2; fn++){
        int r = wc*32 + fn*16 + lr;
        bfr[fn] = *(const bf16x8*)&Bs[hh][r*32 + ((lq + (r>>1))&3)*8];
      }
      #pragma unroll
      for (int fm = 0; fm < 4; fm++)
        #pragma unroll
        for (int fn = 0; fn < 2; fn++)
          acc[fm][fn] = __builtin_amdgcn_mfma_f32_16x16x32_bf16(af[fm], bfr[fn], acc[fm][fn], 0, 0, 0);
    }
  }
  #pragma unroll
  for (int fm = 0; fm < 4; fm++)
    #pragma unroll
    for (int fn = 0; fn < 2; fn++)
      #pragma unroll
      for (int rr = 0; rr < 4; rr++){
        int r = bm + wr*64 + fm*16 + lq*4 + rr;
        int c = bn + wc*32 + fn*16 + lr;
        size_t o = (size_t)r*N + c;
        float v = acc[fm][fn][rr] + bias[c];
        if (HAS_RES){
          if (RES_BF16) v += bf2f(((const unsigned short*)res)[o]);
          else          v += ((const float*)res)[o];
        }
        if (OUT_BF16) ((unsigned short*)Cv)[o] = f2bf(v);
        else          ((float*)Cv)[o] = v;
      }
}

// ---- MFMA qkv GEMM, BK=64; q/k scatter, V TRANSPOSED to vt[bh][d][k] ----
__global__ __launch_bounds__(256) void mqkv(const unsigned short* __restrict__ A,
    const unsigned short* __restrict__ Bt, const float* __restrict__ bias,
    unsigned short* __restrict__ qh, unsigned short* __restrict__ kh, unsigned short* __restrict__ vt){
  const int K = D_;
  __shared__ unsigned short As[2][128*32];
  __shared__ unsigned short Bs[2][128*32];
  const int tid = threadIdx.x;
  const int bm = blockIdx.y*128, bn = blockIdx.x*128;
  const int lane = tid & 63, lq = lane >> 4, lr = lane & 15;
  const int wv = tid >> 6, wr = wv >> 1, wc = wv & 1;
  f32x4 acc[4][4] = {};
  int4v ra[2][2], rb[2][2];
  #pragma unroll
  for (int hh = 0; hh < 2; hh++)
    #pragma unroll
    for (int i = 0; i < 2; i++){
      int f = tid + i*256; int row = f>>2, s = f&3;
      ra[hh][i] = *(const int4v*)&A[(size_t)(bm+row)*K + hh*32 + s*8];
      rb[hh][i] = *(const int4v*)&Bt[(size_t)(bn+row)*K + hh*32 + s*8];
    }
  for (int k0 = 0; k0 < K; k0 += 64){
    __syncthreads();
    #pragma unroll
    for (int hh = 0; hh < 2; hh++)
      #pragma unroll
      for (int i = 0; i < 2; i++){
        int f = tid + i*256; int row = f>>2, s = f&3;
        int off = row*32 + ((s + (row>>1))&3)*8;
        *(int4v*)&As[hh][off] = ra[hh][i];
        *(int4v*)&Bs[hh][off] = rb[hh][i];
      }
    __syncthreads();
    if (k0 + 64 < K){
      #pragma unroll
      for (int hh = 0; hh < 2; hh++){
        int kn = k0 + 64 + hh*32;
        #pragma unroll
        for (int i = 0; i < 2; i++){
          int f = tid + i*256; int row = f>>2, s = f&3;
          ra[hh][i] = *(const int4v*)&A[(size_t)(bm+row)*K + kn + s*8];
          rb[hh][i] = *(const int4v*)&Bt[(size_t)(bn+row)*K + kn + s*8];
        }
      }
    }
    #pragma unroll
    for (int hh = 0; hh < 2; hh++){
      bf16x8 af[4], bfr[4];
      #pragma unroll
      for (int fm = 0; fm < 4; fm++){
        int r = wr*64 + fm*16 + lr;
        af[fm] = *(const bf16x8*)&As[hh][r*32 + ((lq + (r>>1))&3)*8];
      }
      #pragma unroll
      for (int fn = 0; fn < 4; fn++){
        int r = wc*64 + fn*16 + lr;
        bfr[fn] = *(const bf16x8*)&Bs[hh][r*32 + ((lq + (r>>1))&3)*8];
      }
      #pragma unroll
      for (int fm = 0; fm < 4; fm++)
        #pragma unroll
        for (int fn = 0; fn < 4; fn++)
          acc[fm][fn] = __builtin_amdgcn_mfma_f32_16x16x32_bf16(af[fm], bfr[fn], acc[fm][fn], 0, 0, 0);
    }
  }
  #pragma unroll
  for (int fm = 0; fm < 4; fm++)
    #pragma unroll
    for (int fn = 0; fn < 4; fn++){
      int cbase = bn + wc*64 + fn*16 + lr;
      float bv = bias[cbase];
      if (cbase < 2*D_){
        unsigned short* dst = (cbase < D_) ? qh : kh;
        int cc = cbase & (D_-1);
        int u = cc >> 6, d2 = cc & 63;
        #pragma unroll
        for (int rr = 0; rr < 4; rr++){
          int r = bm + wr*64 + fm*16 + lq*4 + rr;
          int b = r >> 10, s = r & (S_-1);
          int h = s >> 6;
          int s2 = ((s & 63) << 4) + u;
          size_t off = (((size_t)(b*H_ + h))*S_ + s2)*HD_ + d2;
          dst[off] = f2bf(acc[fm][fn][rr] + bv);
        }
      } else {
        int cc = cbase - 2*D_;
        int u = cc >> 6, d2 = cc & 63;
        #pragma unroll
        for (int rr = 0; rr < 4; rr++){
          int r = bm + wr*64 + fm*16 + lq*4 + rr;
          int b = r >> 10, s = r & (S_-1);
          int h = s >> 6;
          int s2 = ((s & 63) << 4) + u;
          size_t off = (((size_t)(b*H_ + h))*HD_ + d2)*S_ + s2;   // vt[bh][d][k]
          vt[off] = f2bf(acc[fm][fn][rr] + bv);
        }
      }
    }
}

// ---- MFMA GEGLU, BK=64, prefetch distance 2 (named reg sets, rule #20) ----
#define GG_LOAD(SET, KOFF)                                                     \
  { int kb = (KOFF);                                                           \
    _Pragma("unroll")                                                          \
    for (int hh = 0; hh < 2; hh++){                                            \
      _Pragma("unroll")                                                        \
      for (int i = 0; i < 2; i++){                                             \
        int f = tid + i*256; int row = f>>2, s = f&3;                          \
        ra##SET[hh][i] = *(const int4v*)&A[(size_t)(bm+row)*K + kb + hh*32 + s*8]; \
      }                                                                        \
      { int row = tid>>2, s = tid&3;                                           \
        rba##SET[hh] = *(const int4v*)&Wt[(size_t)(bn+row)*K + kb + hh*32 + s*8]; \
        rbg##SET[hh] = *(const int4v*)&Wt[(size_t)(FF_+bn+row)*K + kb + hh*32 + s*8]; \
      }                                                                        \
    } }

#define GG_WRITE(SET)                                                          \
  { _Pragma("unroll")                                                          \
    for (int hh = 0; hh < 2; hh++){                                            \
      _Pragma("unroll")                                                        \
      for (int i = 0; i < 2; i++){                                             \
        int f = tid + i*256; int row = f>>2, s = f&3;                          \
        *(int4v*)&As[hh][row*32 + ((s + (row>>1))&3)*8] = ra##SET[hh][i];      \
      }                                                                        \
      { int row = tid>>2, s = tid&3;                                           \
        int off = row*32 + ((s + (row>>1))&3)*8;                               \
        *(int4v*)&Ba[hh][off] = rba##SET[hh];                                  \
        *(int4v*)&Bg[hh][off] = rbg##SET[hh];                                  \
      }                                                                        \
    } }

#define GG_COMPUTE                                                             \
  { _Pragma("unroll")                                                          \
    for (int hh = 0; hh < 2; hh++){                                            \
      bf16x8 af[4], fa[2], fg[2];                                              \
      _Pragma("unroll")                                                        \
      for (int fm = 0; fm < 4; fm++){                                          \
        int r = wr*64 + fm*16 + lr;                                            \
        af[fm] = *(const bf16x8*)&As[hh][r*32 + ((lq + (r>>1))&3)*8];          \
      }                                                                        \
      _Pragma("unroll")                                                        \
      for (int fn = 0; fn < 2; fn++){                                          \
        int r = wc*32 + fn*16 + lr;                                            \
        int off = r*32 + ((lq + (r>>1))&3)*8;                                  \
        fa[fn] = *(const bf16x8*)&Ba[hh][off];                                 \
        fg[fn] = *(const bf16x8*)&Bg[hh][off];                                 \
      }                                                                        \
      _Pragma("unroll")                                                        \
      for (int fm = 0; fm < 4; fm++)                                           \
        _Pragma("unroll")                                                      \
        for (int fn = 0; fn < 2; fn++){                                        \
          aa[fm][fn] = __builtin_amdgcn_mfma_f32_16x16x32_bf16(af[fm], fa[fn], aa[fm][fn], 0, 0, 0); \
          ag[fm][fn] = __builtin_amdgcn_mfma_f32_16x16x32_bf16(af[fm], fg[fn], ag[fm][fn], 0, 0, 0); \
        }                                                                      \
    } }

__global__ __launch_bounds__(256) void mgeglu(const unsigned short* __restrict__ A,
    const unsigned short* __restrict__ Wt, const float* __restrict__ bgp, unsigned short* __restrict__ act){
  const int K = FF_;
  __shared__ unsigned short As[2][128*32];
  __shared__ unsigned short Ba[2][64*32];
  __shared__ unsigned short Bg[2][64*32];
  const int tid = threadIdx.x;
  const int bm = blockIdx.y*128, bn = blockIdx.x*64;
  const int lane = tid & 63, lq = lane >> 4, lr = lane & 15;
  const int wv = tid >> 6, wr = wv >> 1, wc = wv & 1;
  f32x4 aa[4][2] = {};
  f32x4 ag[4][2] = {};
  int4v raX[2][2], rbaX[2], rbgX[2];   // set X: holds data for phase k0
  int4v raY[2][2], rbaY[2], rbgY[2];   // set Y: holds data for phase k0+64
  GG_LOAD(X, 0)
  GG_LOAD(Y, 64)
  for (int k0 = 0; k0 < K; k0 += 128){
    // ---- phase X: k = k0 .. k0+63 ----
    __syncthreads();
    GG_WRITE(X)
    __syncthreads();
    if (k0 + 128 < K) GG_LOAD(X, k0 + 128)
    GG_COMPUTE
    // ---- phase Y: k = k0+64 .. k0+127 ----
    __syncthreads();
    GG_WRITE(Y)
    __syncthreads();
    if (k0 + 192 < K) GG_LOAD(Y, k0 + 192)
    GG_COMPUTE
  }
  #pragma unroll
  for (int fm = 0; fm < 4; fm++)
    #pragma unroll
    for (int fn = 0; fn < 2; fn++)
      #pragma unroll
      for (int rr = 0; rr < 4; rr++){
        int r = bm + wr*64 + fm*16 + lq*4 + rr;
        int c = bn + wc*32 + fn*16 + lr;
        float a = aa[fm][fn][rr] + bgp[c];
        float g = ag[fm][fn][rr] + bgp[FF_ + c];
        act[(size_t)r*FF_ + c] = f2bf(gelu_gate(a, g));
      }
}

// ---- mstats: per-row softmax stats (m, l) via QK^T recompute (swizzled) ----
__global__ __launch_bounds__(256) void mstats(const unsigned short* __restrict__ qh,
    const unsigned short* __restrict__ kh, float2* __restrict__ stats){
  int qt = blockIdx.x, bh = blockIdx.y;
  xcd_swz(qt, bh);
  const int tid = threadIdx.x;
  const int lane = tid & 63, lq = lane >> 4, lr = lane & 15;
  const int wv = tid >> 6, wr = wv >> 1, wc = wv & 1;
  __shared__ unsigned short Qs[128*64];
  __shared__ unsigned short Ks[128*64];
  __shared__ float2 st[2][2][64];
  const unsigned short* Qp = qh + ((size_t)bh*S_ + qt*128)*HD_;
  #pragma unroll
  for (int i = 0; i < 4; i++){
    int f = tid + i*256;
    int row = f >> 3, s = f & 7;
    *(int4v*)&Qs[row*64 + ((s + row)&7)*8] = *(const int4v*)&Qp[(size_t)row*HD_ + s*8];
  }
  float m[4][4], l[4][4];
  #pragma unroll
  for (int fm = 0; fm < 4; fm++)
    #pragma unroll
    for (int rr = 0; rr < 4; rr++){ m[fm][rr] = -3.4e38f; l[fm][rr] = 0.f; }
  const int qg0 = qt*128;
  for (int kt = 0; kt <= qt; kt++){
    __syncthreads();
    const unsigned short* Kp = kh + ((size_t)bh*S_ + kt*128)*HD_;
    #pragma unroll
    for (int i = 0; i < 4; i++){
      int f = tid + i*256;
      int row = f >> 3, s = f & 7;
      *(int4v*)&Ks[row*64 + ((s + row)&7)*8] = *(const int4v*)&Kp[(size_t)row*HD_ + s*8];
    }
    __syncthreads();
    f32x4 acc[4][4] = {};
    #pragma unroll
    for (int ks = 0; ks < 2; ks++){
      bf16x8 af[4], bfr[4];
      #pragma unroll
      for (int fm = 0; fm < 4; fm++){
        int r = wr*64 + fm*16 + lr;
        af[fm] = *(const bf16x8*)&Qs[r*64 + ((ks*4+lq + r)&7)*8];
      }
      #pragma unroll
      for (int fn = 0; fn < 4; fn++){
        int r = wc*64 + fn*16 + lr;
        bfr[fn] = *(const bf16x8*)&Ks[r*64 + ((ks*4+lq + r)&7)*8];
      }
      #pragma unroll
      for (int fm = 0; fm < 4; fm++)
        #pragma unroll
        for (int fn = 0; fn < 4; fn++)
          acc[fm][fn] = __builtin_amdgcn_mfma_f32_16x16x32_bf16(af[fm], bfr[fn], acc[fm][fn], 0, 0, 0);
    }
    const int kg0 = kt*128;
    #pragma unroll
    for (int fm = 0; fm < 4; fm++)
      #pragma unroll
      for (int rr = 0; rr < 4; rr++){
        int r = wr*64 + fm*16 + lq*4 + rr;
        float v0 = (kg0 + wc*64 +  0 + lr <= qg0 + r) ? acc[fm][0][rr]*(1.f/32.f) : 0.f;
        float v1 = (kg0 + wc*64 + 16 + lr <= qg0 + r) ? acc[fm][1][rr]*(1.f/32.f) : 0.f;
        float v2 = (kg0 + wc*64 + 32 + lr <= qg0 + r) ? acc[fm][2][rr]*(1.f/32.f) : 0.f;
        float v3 = (kg0 + wc*64 + 48 + lr <= qg0 + r) ? acc[fm][3][rr]*(1.f/32.f) : 0.f;
        float tmax = fmaxf(fmaxf(v0,v1), fmaxf(v2,v3));
        tmax = fmaxf(tmax, __shfl_xor(tmax,1));
        tmax = fmaxf(tmax, __shfl_xor(tmax,2));
        tmax = fmaxf(tmax, __shfl_xor(tmax,4));
        tmax = fmaxf(tmax, __shfl_xor(tmax,8));
        float mn = fmaxf(m[fm][rr], tmax);
        float se = __expf(v0-mn)+__expf(v1-mn)+__expf(v2-mn)+__expf(v3-mn);
        se += __shfl_xor(se,1); se += __shfl_xor(se,2);
        se += __shfl_xor(se,4); se += __shfl_xor(se,8);
        l[fm][rr] = l[fm][rr]*__expf(m[fm][rr]-mn) + se;
        m[fm][rr] = mn;
      }
  }
  if (lr == 0){
    #pragma unroll
    for (int fm = 0; fm < 4; fm++)
      #pragma unroll
      for (int rr = 0; rr < 4; rr++){
        float2 v; v.x = m[fm][rr]; v.y = l[fm][rr];
        st[wr][wc][fm*16 + lq*4 + rr] = v;
      }
  }
  __syncthreads();
  if (wc == 0 && lr == 0){
    const float nz = (float)((7 - qt)*128);
    #pragma unroll
    for (int fm = 0; fm < 4; fm++)
      #pragma unroll
      for (int rr = 0; rr < 4; rr++){
        int r64 = fm*16 + lq*4 + rr;
        float2 a = st[wr][0][r64], b = st[wr][1][r64];
        float mf = fmaxf(a.x, b.x);
        float lf = a.y*__expf(a.x-mf) + b.y*__expf(b.x-mf);
        if (nz > 0.f){
          float mz = fmaxf(mf, 0.f);
          lf = lf*__expf(mf-mz) + nz*__expf(-mz);
          mf = mz;
        }
        float2 o; o.x = mf; o.y = lf;
        stats[(size_t)bh*S_ + qt*128 + wr*64 + r64] = o;
      }
  }
}

// ---- mpv: recompute QK^T, P=exp(v-m)/l, write P to d_out, fused P@V (swizzled) ----
__global__ __launch_bounds__(256) void mpv(const unsigned short* __restrict__ qh,
    const unsigned short* __restrict__ kh, const unsigned short* __restrict__ vt,
    const float2* __restrict__ stats, float* __restrict__ attn, unsigned short* __restrict__ ctx){
  int qt = blockIdx.x, bh = blockIdx.y;
  xcd_swz(qt, bh);
  const int b = bh >> 4, h = bh & 15;
  const int tid = threadIdx.x;
  const int lane = tid & 63, lq = lane >> 4, lr = lane & 15;
  const int wv = tid >> 6, wr = wv >> 1, wc = wv & 1;
  __shared__ unsigned short Qs[128*64];
  __shared__ unsigned short Ks[128*64];
  __shared__ unsigned short Pt[128*128];
  __shared__ unsigned short Vt[64*128];
  const unsigned short* Qp = qh + ((size_t)bh*S_ + qt*128)*HD_;
  const unsigned short* Vp = vt + (size_t)bh*HD_*S_;
  float* Ap = attn + ((size_t)bh*S_ + qt*128)*S_;
  #pragma unroll
  for (int i = 0; i < 4; i++){
    int f = tid + i*256;
    int row = f >> 3, s = f & 7;
    *(int4v*)&Qs[row*64 + ((s + row)&7)*8] = *(const int4v*)&Qp[(size_t)row*HD_ + s*8];
  }
  float mS[4][4], lI[4][4];
  #pragma unroll
  for (int fm = 0; fm < 4; fm++)
    #pragma unroll
    for (int rr = 0; rr < 4; rr++){
      float2 s2 = stats[(size_t)bh*S_ + qt*128 + wr*64 + fm*16 + lq*4 + rr];
      mS[fm][rr] = s2.x; lI[fm][rr] = 1.f / s2.y;
    }
  const int qg0 = qt*128;
  f32x4 oacc[4][2] = {};
  for (int kt = 0; kt < 8; kt++){
    __syncthreads();
    #pragma unroll
    for (int i = 0; i < 4; i++){
      int f = tid + i*256;
      int row = f >> 4, s = f & 15;
      *(int4v*)&Vt[row*128 + ((s + row)&15)*8] = *(const int4v*)&Vp[(size_t)row*S_ + kt*128 + s*8];
    }
    if (kt <= qt){
      const unsigned short* Kp = kh + ((size_t)bh*S_ + kt*128)*HD_;
      #pragma unroll
      for (int i = 0; i < 4; i++){
        int f = tid + i*256;
        int row = f >> 3, s = f & 7;
        *(int4v*)&Ks[row*64 + ((s + row)&7)*8] = *(const int4v*)&Kp[(size_t)row*HD_ + s*8];
      }
      __syncthreads();
      f32x4 acc[4][4] = {};
      #pragma unroll
      for (int ks = 0; ks < 2; ks++){
        bf16x8 af[4], bfr[4];
        #pragma unroll
        for (int fm = 0; fm < 4; fm++){
          int r = wr*64 + fm*16 + lr;
          af[fm] = *(const bf16x8*)&Qs[r*64 + ((ks*4+lq + r)&7)*8];
        }
        #pragma unroll
        for (int fn = 0; fn < 4; fn++){
          int r = wc*64 + fn*16 + lr;
          bfr[fn] = *(const bf16x8*)&Ks[r*64 + ((ks*4+lq + r)&7)*8];
        }
        #pragma unroll
        for (int fm = 0; fm < 4; fm++)
          #pragma unroll
          for (int fn = 0; fn < 4; fn++)
            acc[fm][fn] = __builtin_amdgcn_mfma_f32_16x16x32_bf16(af[fm], bfr[fn], acc[fm][fn], 0, 0, 0);
      }
      const int kg0 = kt*128;
      #pragma unroll
      for (int fm = 0; fm < 4; fm++)
        #pragma unroll
        for (int fn = 0; fn < 4; fn++)
          #pragma unroll
          for (int rr = 0; rr < 4; rr++){
            int r = wr*64 + fm*16 + lq*4 + rr;
            int c = wc*64 + fn*16 + lr;
            float v = (kg0 + c <= qg0 + r) ? acc[fm][fn][rr]*(1.f/32.f) : 0.f;
            float p = __expf(v - mS[fm][rr]) * lI[fm][rr];
            Ap[(size_t)r*S_ + kg0 + c] = p;
            Pt[r*128 + (((c>>3) + r)&15)*8 + (c&7)] = f2bf(p);
          }
      __syncthreads();
    } else {
      __syncthreads();
      int rt = tid >> 1, hk = tid & 1;
      float2 srow = stats[(size_t)bh*S_ + qt*128 + rt];
      float p = __expf(-srow.x) * (1.f / srow.y);
      unsigned short pb = f2bf(p);
      int rep = (unsigned)pb | ((unsigned)pb << 16);
      int4v pv = {rep, rep, rep, rep};
      float4 pf = {p, p, p, p};
      #pragma unroll
      for (int sl = 0; sl < 8; sl++){
        int slot = hk*8 + sl;
        *(int4v*)&Pt[rt*128 + ((slot + rt)&15)*8] = pv;
        *(float4*)&Ap[(size_t)rt*S_ + kt*128 + hk*64 + sl*8] = pf;
        *(float4*)&Ap[(size_t)rt*S_ + kt*128 + hk*64 + sl*8 + 4] = pf;
      }
      __syncthreads();
    }
    #pragma unroll
    for (int ks = 0; ks < 4; ks++){
      bf16x8 af[4], bfv[2];
      #pragma unroll
      for (int fm = 0; fm < 4; fm++){
        int r = wr*64 + fm*16 + lr;
        af[fm] = *(const bf16x8*)&Pt[r*128 + ((ks*4+lq + r)&15)*8];
      }
      #pragma unroll
      for (int fn = 0; fn < 2; fn++){
        int r = wc*32 + fn*16 + lr;
        bfv[fn] = *(const bf16x8*)&Vt[r*128 + ((ks*4+lq + r)&15)*8];
      }
      #pragma unroll
      for (int fm = 0; fm < 4; fm++)
        #pragma unroll
        for (int fn = 0; fn < 2; fn++)
          oacc[fm][fn] = __builtin_amdgcn_mfma_f32_16x16x32_bf16(af[fm], bfv[fn], oacc[fm][fn], 0, 0, 0);
    }
  }
  #pragma unroll
  for (int fm = 0; fm < 4; fm++)
    #pragma unroll
    for (int fn = 0; fn < 2; fn++){
      int d = wc*32 + fn*16 + lr;
      #pragma unroll
      for (int rr = 0; rr < 4; rr++){
        int q = qt*128 + wr*64 + fm*16 + lq*4 + rr;
        size_t orow = ((size_t)b*S_ + h*HD_ + (q>>4)) * D_ + ((q&15)<<6) + d;
        ctx[orow] = f2bf(oacc[fm][fn][rr]);
      }
    }
}

// ---- xcur = bf2f(lnb) + att ----
__global__ __launch_bounds__(256) void addbf(const unsigned short* __restrict__ a,
    const float* __restrict__ b, float* __restrict__ c){
  size_t i = ((size_t)blockIdx.x*256 + threadIdx.x)*4;
  ushort4 av = *(const ushort4*)&a[i];
  float4 bv = *(const float4*)&b[i];
  float4 o = {bf2f(av.x)+bv.x, bf2f(av.y)+bv.y, bf2f(av.z)+bv.z, bf2f(av.w)+bv.w};
  *(float4*)&c[i] = o;
}

// ============================================================================

extern "C" void kernel_launch(void* const* d_in, const int* in_sizes, int n_in,
                              void* d_out, int out_size, void* d_ws, size_t ws_size,
                              hipStream_t stream){
  const float* x0     = (const float*)d_in[0];
  const float* ln1_s  = (const float*)d_in[1];
  const float* ln1_b  = (const float*)d_in[2];
  const float* w_qkv1 = (const float*)d_in[3];
  const float* b_qkv1 = (const float*)d_in[4];
  const float* w_o1   = (const float*)d_in[5];
  const float* b_o1   = (const float*)d_in[6];
  const float* ln2_s  = (const float*)d_in[7];
  const float* ln2_b  = (const float*)d_in[8];
  const float* w_qkv2 = (const float*)d_in[9];
  const float* b_qkv2 = (const float*)d_in[10];
  const float* w_o2   = (const float*)d_in[11];
  const float* b_o2   = (const float*)d_in[12];
  const float* ln3_s  = (const float*)d_in[13];
  const float* ln3_b  = (const float*)d_in[14];
  const float* w1     = (const float*)d_in[15];
  const float* b1     = (const float*)d_in[16];
  const float* wg     = (const float*)d_in[17];
  const float* bg     = (const float*)d_in[18];
  const float* w2     = (const float*)d_in[19];
  const float* b2     = (const float*)d_in[20];

  const size_t MB_ = 1u<<20;
  if (ws_size < 148*MB_) return;   // harness provides >=148MB (verified)
  float* out_x = (float*)d_out;
  float* attn1 = out_x + 2*MB_;
  float* attn2 = attn1 + 32*MB_;
  dim3 blk(256);

  char* w8 = (char*)d_ws;
  float* att  = (float*)(w8 + 0);
  float* xcur = (float*)(w8 + 8*MB_);
  unsigned short* lnb     = (unsigned short*)(w8 + 16*MB_);
  unsigned short* wqkv1t  = (unsigned short*)(w8 + 20*MB_);
  unsigned short* wqkv2t  = (unsigned short*)(w8 + 26*MB_);
  unsigned short* wo1t    = (unsigned short*)(w8 + 32*MB_);
  unsigned short* wo2t    = (unsigned short*)(w8 + 34*MB_);
  unsigned short* w1t     = (unsigned short*)(w8 + 36*MB_);
  unsigned short* w2t     = (unsigned short*)(w8 + 44*MB_);
  unsigned short* wgt     = (unsigned short*)(w8 + 52*MB_);
  unsigned short* qhb     = (unsigned short*)(w8 + 116*MB_);
  unsigned short* khb     = (unsigned short*)(w8 + 120*MB_);
  unsigned short* vtb     = (unsigned short*)(w8 + 124*MB_);
  unsigned short* ctxb    = (unsigned short*)(w8 + 128*MB_);
  unsigned short* hbufb   = (unsigned short*)(w8 + 116*MB_);
  unsigned short* actb    = (unsigned short*)(w8 + 132*MB_);
  float2* stats           = (float2*)(w8 + 132*MB_);   // attention-phase only

  tcvt_all<<<49152, blk, 0, stream>>>(w_qkv1, w_qkv2, w_o1, w_o2, w1, wg, w2,
                                      wqkv1t, wqkv2t, wo1t, wo2t, w1t, wgt, w2t);
  // ---- layer 1 ----
  lnb_k<<<NROW_, blk, 0, stream>>>(x0, ln1_s, ln1_b, lnb);
  mqkv<<<dim3(24,16), blk, 0, stream>>>(lnb, wqkv1t, b_qkv1, qhb, khb, vtb);
  mstats<<<dim3(8,32), blk, 0, stream>>>(qhb, khb, stats);
  mpv<<<dim3(8,32), blk, 0, stream>>>(qhb, khb, vtb, stats, attn1, ctxb);
  mgemm64<true,true,false><<<dim3(16,16), blk, 0, stream>>>(ctxb, wo1t, b_o1, lnb, xcur, NROW_, D_, D_);
  // ---- layer 2 ----
  lnb_k<<<NROW_, blk, 0, stream>>>(xcur, ln2_s, ln2_b, lnb);
  mqkv<<<dim3(24,16), blk, 0, stream>>>(lnb, wqkv2t, b_qkv2, qhb, khb, vtb);
  mstats<<<dim3(8,32), blk, 0, stream>>>(qhb, khb, stats);
  mpv<<<dim3(8,32), blk, 0, stream>>>(qhb, khb, vtb, stats, attn2, ctxb);
  mgemm64<false,false,false><<<dim3(16,16), blk, 0, stream>>>(ctxb, wo2t, b_o2, nullptr, att, NROW_, D_, D_);
  addbf<<<2048, blk, 0, stream>>>(lnb, att, xcur);
  // ---- FFN ----
  lnb_k<<<NROW_, blk, 0, stream>>>(xcur, ln3_s, ln3_b, lnb);
  mgemm<false,false,true><<<dim3(32,16), blk, 0, stream>>>(lnb, w1t, b1, nullptr, hbufb, NROW_, FF_, D_);
  mgeglu<<<dim3(64,16), blk, 0, stream>>>(hbufb, wgt, bg, actb);
  mgemm64<true,false,false><<<dim3(16,16), blk, 0, stream>>>(actb, w2t, b2, att, out_x, NROW_, D_, FF_);
}

// Round 21
// 572.257 us; speedup vs baseline: 1.1114x; 1.1114x over previous
//
#include <hip/hip_runtime.h>
#include <hip/hip_bf16.h>

#define B_ 2
#define S_ 1024
#define D_ 1024
#define H_ 16
#define HD_ 64
#define FF_ 4096
#define NROW_ (B_*S_)

typedef __hip_bfloat16 bf16;
typedef float f32x4 __attribute__((ext_vector_type(4)));
typedef int int4v __attribute__((ext_vector_type(4)));
typedef __bf16 bf16x8 __attribute__((ext_vector_type(8)));

__device__ __forceinline__ float bf2f(unsigned short u){
  return __uint_as_float((unsigned)u << 16);
}
__device__ __forceinline__ unsigned short f2bf(float f){
  unsigned u = __float_as_uint(f);
  return (unsigned short)((u + 0x7FFFu + ((u >> 16) & 1u)) >> 16);
}
__device__ __forceinline__ float gelu_gate(float a, float g){
  float t = tanhf(0.7978845608f * g * (1.f + 0.044715f * g * g));
  return a * 0.5f * g * (1.f + t);
}
// bijective XCD swizzle — ONLY for mstats/mpv (round-15 lesson).
__device__ __forceinline__ void xcd_swz(int& bx, int& by){
  int nx = gridDim.x, tot = nx * gridDim.y;
  int flat = by * nx + bx;
  int cpx = tot >> 3;
  int w = (flat & 7) * cpx + (flat >> 3);
  bx = w % nx; by = w / nx;
}

// ============================================================================
// ===========================  FAST PATH (MFMA)  =============================
// ============================================================================

// ---- fused transpose+convert for all 7 weights: f32 [K][N] -> bf16 [N][K] ----
__global__ __launch_bounds__(256) void tcvt_all(
    const float* __restrict__ w_qkv1, const float* __restrict__ w_qkv2,
    const float* __restrict__ w_o1,   const float* __restrict__ w_o2,
    const float* __restrict__ w1,     const float* __restrict__ wg,
    const float* __restrict__ w2,
    unsigned short* __restrict__ t_qkv1, unsigned short* __restrict__ t_qkv2,
    unsigned short* __restrict__ t_o1,   unsigned short* __restrict__ t_o2,
    unsigned short* __restrict__ t_w1,   unsigned short* __restrict__ t_wg,
    unsigned short* __restrict__ t_w2){
  __shared__ float tile[32][33];
  int id = blockIdx.x;
  const float* W; unsigned short* Wt; int K, N, t0;
  if      (id <  3072){ W=w_qkv1; Wt=t_qkv1; K=1024; N=3072; t0=0; }
  else if (id <  6144){ W=w_qkv2; Wt=t_qkv2; K=1024; N=3072; t0=3072; }
  else if (id <  7168){ W=w_o1;   Wt=t_o1;   K=1024; N=1024; t0=6144; }
  else if (id <  8192){ W=w_o2;   Wt=t_o2;   K=1024; N=1024; t0=7168; }
  else if (id < 12288){ W=w1;     Wt=t_w1;   K=1024; N=4096; t0=8192; }
  else if (id < 45056){ W=wg;     Wt=t_wg;   K=4096; N=8192; t0=12288; }
  else               { W=w2;     Wt=t_w2;   K=4096; N=1024; t0=45056; }
  int tl = id - t0;
  int nx = N >> 5;
  int n0 = (tl % nx) * 32, k0 = (tl / nx) * 32;
  const int t = threadIdx.x;
  #pragma unroll
  for (int i = 0; i < 4; i++){
    int idx = t + i*256; int r = idx>>5, c = idx&31;
    tile[r][c] = W[(size_t)(k0+r)*N + n0 + c];
  }
  __syncthreads();
  #pragma unroll
  for (int i = 0; i < 4; i++){
    int idx = t + i*256; int r = idx>>5, c = idx&31;
    Wt[(size_t)(n0+r)*K + k0 + c] = f2bf(tile[c][r]);
  }
}

// ---- LayerNorm: f32 in -> bf16 out ----
__global__ __launch_bounds__(256) void lnb_k(const float* __restrict__ x,
    const float* __restrict__ sc, const float* __restrict__ bi, unsigned short* __restrict__ y){
  const int row = blockIdx.x;
  const int t = threadIdx.x;
  const float* xr = x + (size_t)row * D_;
  float4 v = *(const float4*)&xr[t*4];
  __shared__ float red[8];
  float sum = v.x + v.y + v.z + v.w;
  #pragma unroll
  for (int o = 32; o > 0; o >>= 1) sum += __shfl_down(sum, o);
  if ((t & 63) == 0) red[t >> 6] = sum;
  __syncthreads();
  if (t == 0) red[4] = (red[0]+red[1]+red[2]+red[3]) * (1.f / D_);
  __syncthreads();
  const float mean = red[4];
  const float dx = v.x-mean, dy = v.y-mean, dz = v.z-mean, dw = v.w-mean;
  float sq = dx*dx + dy*dy + dz*dz + dw*dw;
  #pragma unroll
  for (int o = 32; o > 0; o >>= 1) sq += __shfl_down(sq, o);
  if ((t & 63) == 0) red[t >> 6] = sq;
  __syncthreads();
  if (t == 0) red[5] = (red[0]+red[1]+red[2]+red[3]) * (1.f / D_);
  __syncthreads();
  const float rstd = rsqrtf(red[5] + 1e-6f);
  float4 s4 = *(const float4*)&sc[t*4];
  float4 b4 = *(const float4*)&bi[t*4];
  ushort4 ov;
  ov.x = f2bf(dx*rstd*s4.x + b4.x);
  ov.y = f2bf(dy*rstd*s4.y + b4.y);
  ov.z = f2bf(dz*rstd*s4.z + b4.z);
  ov.w = f2bf(dw*rstd*s4.w + b4.w);
  *(ushort4*)&y[(size_t)row*D_ + t*4] = ov;
}

// ---- MFMA GEMM, BK=64, BN=128 (for N>=2048 shapes) ----
template<bool HAS_RES, bool RES_BF16, bool OUT_BF16>
__global__ __launch_bounds__(256) void mgemm(const unsigned short* __restrict__ A,
    const unsigned short* __restrict__ Bt, const float* __restrict__ bias,
    const void* __restrict__ res, void* __restrict__ Cv, int M, int N, int K){
  __shared__ unsigned short As[2][128*32];
  __shared__ unsigned short Bs[2][128*32];
  const int tid = threadIdx.x;
  const int bm = blockIdx.y*128, bn = blockIdx.x*128;
  const int lane = tid & 63, lq = lane >> 4, lr = lane & 15;
  const int wv = tid >> 6, wr = wv >> 1, wc = wv & 1;
  f32x4 acc[4][4] = {};
  int4v ra[2][2], rb[2][2];
  #pragma unroll
  for (int hh = 0; hh < 2; hh++)
    #pragma unroll
    for (int i = 0; i < 2; i++){
      int f = tid + i*256; int row = f>>2, s = f&3;
      ra[hh][i] = *(const int4v*)&A[(size_t)(bm+row)*K + hh*32 + s*8];
      rb[hh][i] = *(const int4v*)&Bt[(size_t)(bn+row)*K + hh*32 + s*8];
    }
  for (int k0 = 0; k0 < K; k0 += 64){
    __syncthreads();
    #pragma unroll
    for (int hh = 0; hh < 2; hh++)
      #pragma unroll
      for (int i = 0; i < 2; i++){
        int f = tid + i*256; int row = f>>2, s = f&3;
        int off = row*32 + ((s + (row>>1))&3)*8;
        *(int4v*)&As[hh][off] = ra[hh][i];
        *(int4v*)&Bs[hh][off] = rb[hh][i];
      }
    __syncthreads();
    if (k0 + 64 < K){
      #pragma unroll
      for (int hh = 0; hh < 2; hh++){
        int kn = k0 + 64 + hh*32;
        #pragma unroll
        for (int i = 0; i < 2; i++){
          int f = tid + i*256; int row = f>>2, s = f&3;
          ra[hh][i] = *(const int4v*)&A[(size_t)(bm+row)*K + kn + s*8];
          rb[hh][i] = *(const int4v*)&Bt[(size_t)(bn+row)*K + kn + s*8];
        }
      }
    }
    #pragma unroll
    for (int hh = 0; hh < 2; hh++){
      bf16x8 af[4], bfr[4];
      #pragma unroll
      for (int fm = 0; fm < 4; fm++){
        int r = wr*64 + fm*16 + lr;
        af[fm] = *(const bf16x8*)&As[hh][r*32 + ((lq + (r>>1))&3)*8];
      }
      #pragma unroll
      for (int fn = 0; fn < 4; fn++){
        int r = wc*64 + fn*16 + lr;
        bfr[fn] = *(const bf16x8*)&Bs[hh][r*32 + ((lq + (r>>1))&3)*8];
      }
      #pragma unroll
      for (int fm = 0; fm < 4; fm++)
        #pragma unroll
        for (int fn = 0; fn < 4; fn++)
          acc[fm][fn] = __builtin_amdgcn_mfma_f32_16x16x32_bf16(af[fm], bfr[fn], acc[fm][fn], 0, 0, 0);
    }
  }
  #pragma unroll
  for (int fm = 0; fm < 4; fm++)
    #pragma unroll
    for (int fn = 0; fn < 4; fn++)
      #pragma unroll
      for (int rr = 0; rr < 4; rr++){
        int r = bm + wr*64 + fm*16 + lq*4 + rr;
        int c = bn + wc*64 + fn*16 + lr;
        size_t o = (size_t)r*N + c;
        float v = acc[fm][fn][rr] + bias[c];
        if (HAS_RES){
          if (RES_BF16) v += bf2f(((const unsigned short*)res)[o]);
          else          v += ((const float*)res)[o];
        }
        if (OUT_BF16) ((unsigned short*)Cv)[o] = f2bf(v);
        else          ((float*)Cv)[o] = v;
      }
}

// ---- MFMA GEMM, BK=64, BN=64 (for N=1024 shapes: grid (16,16)=256 blocks) ----
template<bool HAS_RES, bool RES_BF16, bool OUT_BF16>
__global__ __launch_bounds__(256) void mgemm64(const unsigned short* __restrict__ A,
    const unsigned short* __restrict__ Bt, const float* __restrict__ bias,
    const void* __restrict__ res, void* __restrict__ Cv, int M, int N, int K){
  __shared__ unsigned short As[2][128*32];
  __shared__ unsigned short Bs[2][64*32];
  const int tid = threadIdx.x;
  const int bm = blockIdx.y*128, bn = blockIdx.x*64;
  const int lane = tid & 63, lq = lane >> 4, lr = lane & 15;
  const int wv = tid >> 6, wr = wv >> 1, wc = wv & 1;
  f32x4 acc[4][2] = {};
  int4v ra[2][2], rb[2];
  #pragma unroll
  for (int hh = 0; hh < 2; hh++){
    #pragma unroll
    for (int i = 0; i < 2; i++){
      int f = tid + i*256; int row = f>>2, s = f&3;
      ra[hh][i] = *(const int4v*)&A[(size_t)(bm+row)*K + hh*32 + s*8];
    }
    { int row = tid>>2, s = tid&3;
      rb[hh] = *(const int4v*)&Bt[(size_t)(bn+row)*K + hh*32 + s*8];
    }
  }
  for (int k0 = 0; k0 < K; k0 += 64){
    __syncthreads();
    #pragma unroll
    for (int hh = 0; hh < 2; hh++){
      #pragma unroll
      for (int i = 0; i < 2; i++){
        int f = tid + i*256; int row = f>>2, s = f&3;
        *(int4v*)&As[hh][row*32 + ((s + (row>>1))&3)*8] = ra[hh][i];
      }
      { int row = tid>>2, s = tid&3;
        *(int4v*)&Bs[hh][row*32 + ((s + (row>>1))&3)*8] = rb[hh];
      }
    }
    __syncthreads();
    if (k0 + 64 < K){
      #pragma unroll
      for (int hh = 0; hh < 2; hh++){
        int kn = k0 + 64 + hh*32;
        #pragma unroll
        for (int i = 0; i < 2; i++){
          int f = tid + i*256; int row = f>>2, s = f&3;
          ra[hh][i] = *(const int4v*)&A[(size_t)(bm+row)*K + kn + s*8];
        }
        { int row = tid>>2, s = tid&3;
          rb[hh] = *(const int4v*)&Bt[(size_t)(bn+row)*K + kn + s*8];
        }
      }
    }
    #pragma unroll
    for (int hh = 0; hh < 2; hh++){
      bf16x8 af[4], bfr[2];
      #pragma unroll
      for (int fm = 0; fm < 4; fm++){
        int r = wr*64 + fm*16 + lr;
        af[fm] = *(const bf16x8*)&As[hh][r*32 + ((lq + (r>>1))&3)*8];
      }
      #pragma unroll
      for (int fn = 0; fn < 2; fn++){
        int r = wc*32 + fn*16 + lr;
        bfr[fn] = *(const bf16x8*)&Bs[hh][r*32 + ((lq + (r>>1))&3)*8];
      }
      #pragma unroll
      for (int fm = 0; fm < 4; fm++)
        #pragma unroll
        for (int fn = 0; fn < 2; fn++)
          acc[fm][fn] = __builtin_amdgcn_mfma_f32_16x16x32_bf16(af[fm], bfr[fn], acc[fm][fn], 0, 0, 0);
    }
  }
  #pragma unroll
  for (int fm = 0; fm < 4; fm++)
    #pragma unroll
    for (int fn = 0; fn < 2; fn++)
      #pragma unroll
      for (int rr = 0; rr < 4; rr++){
        int r = bm + wr*64 + fm*16 + lq*4 + rr;
        int c = bn + wc*32 + fn*16 + lr;
        size_t o = (size_t)r*N + c;
        float v = acc[fm][fn][rr] + bias[c];
        if (HAS_RES){
          if (RES_BF16) v += bf2f(((const unsigned short*)res)[o]);
          else          v += ((const float*)res)[o];
        }
        if (OUT_BF16) ((unsigned short*)Cv)[o] = f2bf(v);
        else          ((float*)Cv)[o] = v;
      }
}

// ---- MFMA qkv GEMM, BK=64; q/k scatter, V TRANSPOSED to vt[bh][d][k] ----
__global__ __launch_bounds__(256) void mqkv(const unsigned short* __restrict__ A,
    const unsigned short* __restrict__ Bt, const float* __restrict__ bias,
    unsigned short* __restrict__ qh, unsigned short* __restrict__ kh, unsigned short* __restrict__ vt){
  const int K = D_;
  __shared__ unsigned short As[2][128*32];
  __shared__ unsigned short Bs[2][128*32];
  const int tid = threadIdx.x;
  const int bm = blockIdx.y*128, bn = blockIdx.x*128;
  const int lane = tid & 63, lq = lane >> 4, lr = lane & 15;
  const int wv = tid >> 6, wr = wv >> 1, wc = wv & 1;
  f32x4 acc[4][4] = {};
  int4v ra[2][2], rb[2][2];
  #pragma unroll
  for (int hh = 0; hh < 2; hh++)
    #pragma unroll
    for (int i = 0; i < 2; i++){
      int f = tid + i*256; int row = f>>2, s = f&3;
      ra[hh][i] = *(const int4v*)&A[(size_t)(bm+row)*K + hh*32 + s*8];
      rb[hh][i] = *(const int4v*)&Bt[(size_t)(bn+row)*K + hh*32 + s*8];
    }
  for (int k0 = 0; k0 < K; k0 += 64){
    __syncthreads();
    #pragma unroll
    for (int hh = 0; hh < 2; hh++)
      #pragma unroll
      for (int i = 0; i < 2; i++){
        int f = tid + i*256; int row = f>>2, s = f&3;
        int off = row*32 + ((s + (row>>1))&3)*8;
        *(int4v*)&As[hh][off] = ra[hh][i];
        *(int4v*)&Bs[hh][off] = rb[hh][i];
      }
    __syncthreads();
    if (k0 + 64 < K){
      #pragma unroll
      for (int hh = 0; hh < 2; hh++){
        int kn = k0 + 64 + hh*32;
        #pragma unroll
        for (int i = 0; i < 2; i++){
          int f = tid + i*256; int row = f>>2, s = f&3;
          ra[hh][i] = *(const int4v*)&A[(size_t)(bm+row)*K + kn + s*8];
          rb[hh][i] = *(const int4v*)&Bt[(size_t)(bn+row)*K + kn + s*8];
        }
      }
    }
    #pragma unroll
    for (int hh = 0; hh < 2; hh++){
      bf16x8 af[4], bfr[4];
      #pragma unroll
      for (int fm = 0; fm < 4; fm++){
        int r = wr*64 + fm*16 + lr;
        af[fm] = *(const bf16x8*)&As[hh][r*32 + ((lq + (r>>1))&3)*8];
      }
      #pragma unroll
      for (int fn = 0; fn < 4; fn++){
        int r = wc*64 + fn*16 + lr;
        bfr[fn] = *(const bf16x8*)&Bs[hh][r*32 + ((lq + (r>>1))&3)*8];
      }
      #pragma unroll
      for (int fm = 0; fm < 4; fm++)
        #pragma unroll
        for (int fn = 0; fn < 4; fn++)
          acc[fm][fn] = __builtin_amdgcn_mfma_f32_16x16x32_bf16(af[fm], bfr[fn], acc[fm][fn], 0, 0, 0);
    }
  }
  #pragma unroll
  for (int fm = 0; fm < 4; fm++)
    #pragma unroll
    for (int fn = 0; fn < 4; fn++){
      int cbase = bn + wc*64 + fn*16 + lr;
      float bv = bias[cbase];
      if (cbase < 2*D_){
        unsigned short* dst = (cbase < D_) ? qh : kh;
        int cc = cbase & (D_-1);
        int u = cc >> 6, d2 = cc & 63;
        #pragma unroll
        for (int rr = 0; rr < 4; rr++){
          int r = bm + wr*64 + fm*16 + lq*4 + rr;
          int b = r >> 10, s = r & (S_-1);
          int h = s >> 6;
          int s2 = ((s & 63) << 4) + u;
          size_t off = (((size_t)(b*H_ + h))*S_ + s2)*HD_ + d2;
          dst[off] = f2bf(acc[fm][fn][rr] + bv);
        }
      } else {
        int cc = cbase - 2*D_;
        int u = cc >> 6, d2 = cc & 63;
        #pragma unroll
        for (int rr = 0; rr < 4; rr++){
          int r = bm + wr*64 + fm*16 + lq*4 + rr;
          int b = r >> 10, s = r & (S_-1);
          int h = s >> 6;
          int s2 = ((s & 63) << 4) + u;
          size_t off = (((size_t)(b*H_ + h))*HD_ + d2)*S_ + s2;   // vt[bh][d][k]
          vt[off] = f2bf(acc[fm][fn][rr] + bv);
        }
      }
    }
}

// ---- MFMA GEGLU, BK=64 distance-1 (verified 175us / VGPR 92 shape) ----
__global__ __launch_bounds__(256) void mgeglu(const unsigned short* __restrict__ A,
    const unsigned short* __restrict__ Wt, const float* __restrict__ bgp, unsigned short* __restrict__ act){
  const int K = FF_;
  __shared__ unsigned short As[2][128*32];
  __shared__ unsigned short Ba[2][64*32];
  __shared__ unsigned short Bg[2][64*32];
  const int tid = threadIdx.x;
  const int bm = blockIdx.y*128, bn = blockIdx.x*64;
  const int lane = tid & 63, lq = lane >> 4, lr = lane & 15;
  const int wv = tid >> 6, wr = wv >> 1, wc = wv & 1;
  f32x4 aa[4][2] = {};
  f32x4 ag[4][2] = {};
  int4v ra[2][2], rba[2], rbg[2];
  #pragma unroll
  for (int hh = 0; hh < 2; hh++){
    #pragma unroll
    for (int i = 0; i < 2; i++){
      int f = tid + i*256; int row = f>>2, s = f&3;
      ra[hh][i] = *(const int4v*)&A[(size_t)(bm+row)*K + hh*32 + s*8];
    }
    { int row = tid>>2, s = tid&3;
      rba[hh] = *(const int4v*)&Wt[(size_t)(bn+row)*K + hh*32 + s*8];
      rbg[hh] = *(const int4v*)&Wt[(size_t)(FF_+bn+row)*K + hh*32 + s*8];
    }
  }
  for (int k0 = 0; k0 < K; k0 += 64){
    __syncthreads();
    #pragma unroll
    for (int hh = 0; hh < 2; hh++){
      #pragma unroll
      for (int i = 0; i < 2; i++){
        int f = tid + i*256; int row = f>>2, s = f&3;
        *(int4v*)&As[hh][row*32 + ((s + (row>>1))&3)*8] = ra[hh][i];
      }
      { int row = tid>>2, s = tid&3;
        int off = row*32 + ((s + (row>>1))&3)*8;
        *(int4v*)&Ba[hh][off] = rba[hh];
        *(int4v*)&Bg[hh][off] = rbg[hh];
      }
    }
    __syncthreads();
    if (k0 + 64 < K){
      #pragma unroll
      for (int hh = 0; hh < 2; hh++){
        int kn = k0 + 64 + hh*32;
        #pragma unroll
        for (int i = 0; i < 2; i++){
          int f = tid + i*256; int row = f>>2, s = f&3;
          ra[hh][i] = *(const int4v*)&A[(size_t)(bm+row)*K + kn + s*8];
        }
        { int row = tid>>2, s = tid&3;
          rba[hh] = *(const int4v*)&Wt[(size_t)(bn+row)*K + kn + s*8];
          rbg[hh] = *(const int4v*)&Wt[(size_t)(FF_+bn+row)*K + kn + s*8];
        }
      }
    }
    #pragma unroll
    for (int hh = 0; hh < 2; hh++){
      bf16x8 af[4], fa[2], fg[2];
      #pragma unroll
      for (int fm = 0; fm < 4; fm++){
        int r = wr*64 + fm*16 + lr;
        af[fm] = *(const bf16x8*)&As[hh][r*32 + ((lq + (r>>1))&3)*8];
      }
      #pragma unroll
      for (int fn = 0; fn < 2; fn++){
        int r = wc*32 + fn*16 + lr;
        int off = r*32 + ((lq + (r>>1))&3)*8;
        fa[fn] = *(const bf16x8*)&Ba[hh][off];
        fg[fn] = *(const bf16x8*)&Bg[hh][off];
      }
      #pragma unroll
      for (int fm = 0; fm < 4; fm++)
        #pragma unroll
        for (int fn = 0; fn < 2; fn++){
          aa[fm][fn] = __builtin_amdgcn_mfma_f32_16x16x32_bf16(af[fm], fa[fn], aa[fm][fn], 0, 0, 0);
          ag[fm][fn] = __builtin_amdgcn_mfma_f32_16x16x32_bf16(af[fm], fg[fn], ag[fm][fn], 0, 0, 0);
        }
    }
  }
  #pragma unroll
  for (int fm = 0; fm < 4; fm++)
    #pragma unroll
    for (int fn = 0; fn < 2; fn++)
      #pragma unroll
      for (int rr = 0; rr < 4; rr++){
        int r = bm + wr*64 + fm*16 + lq*4 + rr;
        int c = bn + wc*32 + fn*16 + lr;
        float a = aa[fm][fn][rr] + bgp[c];
        float g = ag[fm][fn][rr] + bgp[FF_ + c];
        act[(size_t)r*FF_ + c] = f2bf(gelu_gate(a, g));
      }
}

// ---- mstats: per-row softmax stats (m, l) via QK^T recompute (swizzled) ----
__global__ __launch_bounds__(256) void mstats(const unsigned short* __restrict__ qh,
    const unsigned short* __restrict__ kh, float2* __restrict__ stats){
  int qt = blockIdx.x, bh = blockIdx.y;
  xcd_swz(qt, bh);
  const int tid = threadIdx.x;
  const int lane = tid & 63, lq = lane >> 4, lr = lane & 15;
  const int wv = tid >> 6, wr = wv >> 1, wc = wv & 1;
  __shared__ unsigned short Qs[128*64];
  __shared__ unsigned short Ks[128*64];
  __shared__ float2 st[2][2][64];
  const unsigned short* Qp = qh + ((size_t)bh*S_ + qt*128)*HD_;
  #pragma unroll
  for (int i = 0; i < 4; i++){
    int f = tid + i*256;
    int row = f >> 3, s = f & 7;
    *(int4v*)&Qs[row*64 + ((s + row)&7)*8] = *(const int4v*)&Qp[(size_t)row*HD_ + s*8];
  }
  float m[4][4], l[4][4];
  #pragma unroll
  for (int fm = 0; fm < 4; fm++)
    #pragma unroll
    for (int rr = 0; rr < 4; rr++){ m[fm][rr] = -3.4e38f; l[fm][rr] = 0.f; }
  const int qg0 = qt*128;
  for (int kt = 0; kt <= qt; kt++){
    __syncthreads();
    const unsigned short* Kp = kh + ((size_t)bh*S_ + kt*128)*HD_;
    #pragma unroll
    for (int i = 0; i < 4; i++){
      int f = tid + i*256;
      int row = f >> 3, s = f & 7;
      *(int4v*)&Ks[row*64 + ((s + row)&7)*8] = *(const int4v*)&Kp[(size_t)row*HD_ + s*8];
    }
    __syncthreads();
    f32x4 acc[4][4] = {};
    #pragma unroll
    for (int ks = 0; ks < 2; ks++){
      bf16x8 af[4], bfr[4];
      #pragma unroll
      for (int fm = 0; fm < 4; fm++){
        int r = wr*64 + fm*16 + lr;
        af[fm] = *(const bf16x8*)&Qs[r*64 + ((ks*4+lq + r)&7)*8];
      }
      #pragma unroll
      for (int fn = 0; fn < 4; fn++){
        int r = wc*64 + fn*16 + lr;
        bfr[fn] = *(const bf16x8*)&Ks[r*64 + ((ks*4+lq + r)&7)*8];
      }
      #pragma unroll
      for (int fm = 0; fm < 4; fm++)
        #pragma unroll
        for (int fn = 0; fn < 4; fn++)
          acc[fm][fn] = __builtin_amdgcn_mfma_f32_16x16x32_bf16(af[fm], bfr[fn], acc[fm][fn], 0, 0, 0);
    }
    const int kg0 = kt*128;
    #pragma unroll
    for (int fm = 0; fm < 4; fm++)
      #pragma unroll
      for (int rr = 0; rr < 4; rr++){
        int r = wr*64 + fm*16 + lq*4 + rr;
        float v0 = (kg0 + wc*64 +  0 + lr <= qg0 + r) ? acc[fm][0][rr]*(1.f/32.f) : 0.f;
        float v1 = (kg0 + wc*64 + 16 + lr <= qg0 + r) ? acc[fm][1][rr]*(1.f/32.f) : 0.f;
        float v2 = (kg0 + wc*64 + 32 + lr <= qg0 + r) ? acc[fm][2][rr]*(1.f/32.f) : 0.f;
        float v3 = (kg0 + wc*64 + 48 + lr <= qg0 + r) ? acc[fm][3][rr]*(1.f/32.f) : 0.f;
        float tmax = fmaxf(fmaxf(v0,v1), fmaxf(v2,v3));
        tmax = fmaxf(tmax, __shfl_xor(tmax,1));
        tmax = fmaxf(tmax, __shfl_xor(tmax,2));
        tmax = fmaxf(tmax, __shfl_xor(tmax,4));
        tmax = fmaxf(tmax, __shfl_xor(tmax,8));
        float mn = fmaxf(m[fm][rr], tmax);
        float se = __expf(v0-mn)+__expf(v1-mn)+__expf(v2-mn)+__expf(v3-mn);
        se += __shfl_xor(se,1); se += __shfl_xor(se,2);
        se += __shfl_xor(se,4); se += __shfl_xor(se,8);
        l[fm][rr] = l[fm][rr]*__expf(m[fm][rr]-mn) + se;
        m[fm][rr] = mn;
      }
  }
  if (lr == 0){
    #pragma unroll
    for (int fm = 0; fm < 4; fm++)
      #pragma unroll
      for (int rr = 0; rr < 4; rr++){
        float2 v; v.x = m[fm][rr]; v.y = l[fm][rr];
        st[wr][wc][fm*16 + lq*4 + rr] = v;
      }
  }
  __syncthreads();
  if (wc == 0 && lr == 0){
    const float nz = (float)((7 - qt)*128);
    #pragma unroll
    for (int fm = 0; fm < 4; fm++)
      #pragma unroll
      for (int rr = 0; rr < 4; rr++){
        int r64 = fm*16 + lq*4 + rr;
        float2 a = st[wr][0][r64], b = st[wr][1][r64];
        float mf = fmaxf(a.x, b.x);
        float lf = a.y*__expf(a.x-mf) + b.y*__expf(b.x-mf);
        if (nz > 0.f){
          float mz = fmaxf(mf, 0.f);
          lf = lf*__expf(mf-mz) + nz*__expf(-mz);
          mf = mz;
        }
        float2 o; o.x = mf; o.y = lf;
        stats[(size_t)bh*S_ + qt*128 + wr*64 + r64] = o;
      }
  }
}

// ---- mpv: recompute QK^T, P=exp(v-m)/l, write P to d_out, fused P@V (swizzled) ----
__global__ __launch_bounds__(256) void mpv(const unsigned short* __restrict__ qh,
    const unsigned short* __restrict__ kh, const unsigned short* __restrict__ vt,
    const float2* __restrict__ stats, float* __restrict__ attn, unsigned short* __restrict__ ctx){
  int qt = blockIdx.x, bh = blockIdx.y;
  xcd_swz(qt, bh);
  const int b = bh >> 4, h = bh & 15;
  const int tid = threadIdx.x;
  const int lane = tid & 63, lq = lane >> 4, lr = lane & 15;
  const int wv = tid >> 6, wr = wv >> 1, wc = wv & 1;
  __shared__ unsigned short Qs[128*64];
  __shared__ unsigned short Ks[128*64];
  __shared__ unsigned short Pt[128*128];
  __shared__ unsigned short Vt[64*128];
  const unsigned short* Qp = qh + ((size_t)bh*S_ + qt*128)*HD_;
  const unsigned short* Vp = vt + (size_t)bh*HD_*S_;
  float* Ap = attn + ((size_t)bh*S_ + qt*128)*S_;
  #pragma unroll
  for (int i = 0; i < 4; i++){
    int f = tid + i*256;
    int row = f >> 3, s = f & 7;
    *(int4v*)&Qs[row*64 + ((s + row)&7)*8] = *(const int4v*)&Qp[(size_t)row*HD_ + s*8];
  }
  float mS[4][4], lI[4][4];
  #pragma unroll
  for (int fm = 0; fm < 4; fm++)
    #pragma unroll
    for (int rr = 0; rr < 4; rr++){
      float2 s2 = stats[(size_t)bh*S_ + qt*128 + wr*64 + fm*16 + lq*4 + rr];
      mS[fm][rr] = s2.x; lI[fm][rr] = 1.f / s2.y;
    }
  const int qg0 = qt*128;
  f32x4 oacc[4][2] = {};
  for (int kt = 0; kt < 8; kt++){
    __syncthreads();
    #pragma unroll
    for (int i = 0; i < 4; i++){
      int f = tid + i*256;
      int row = f >> 4, s = f & 15;
      *(int4v*)&Vt[row*128 + ((s + row)&15)*8] = *(const int4v*)&Vp[(size_t)row*S_ + kt*128 + s*8];
    }
    if (kt <= qt){
      const unsigned short* Kp = kh + ((size_t)bh*S_ + kt*128)*HD_;
      #pragma unroll
      for (int i = 0; i < 4; i++){
        int f = tid + i*256;
        int row = f >> 3, s = f & 7;
        *(int4v*)&Ks[row*64 + ((s + row)&7)*8] = *(const int4v*)&Kp[(size_t)row*HD_ + s*8];
      }
      __syncthreads();
      f32x4 acc[4][4] = {};
      #pragma unroll
      for (int ks = 0; ks < 2; ks++){
        bf16x8 af[4], bfr[4];
        #pragma unroll
        for (int fm = 0; fm < 4; fm++){
          int r = wr*64 + fm*16 + lr;
          af[fm] = *(const bf16x8*)&Qs[r*64 + ((ks*4+lq + r)&7)*8];
        }
        #pragma unroll
        for (int fn = 0; fn < 4; fn++){
          int r = wc*64 + fn*16 + lr;
          bfr[fn] = *(const bf16x8*)&Ks[r*64 + ((ks*4+lq + r)&7)*8];
        }
        #pragma unroll
        for (int fm = 0; fm < 4; fm++)
          #pragma unroll
          for (int fn = 0; fn < 4; fn++)
            acc[fm][fn] = __builtin_amdgcn_mfma_f32_16x16x32_bf16(af[fm], bfr[fn], acc[fm][fn], 0, 0, 0);
      }
      const int kg0 = kt*128;
      #pragma unroll
      for (int fm = 0; fm < 4; fm++)
        #pragma unroll
        for (int fn = 0; fn < 4; fn++)
          #pragma unroll
          for (int rr = 0; rr < 4; rr++){
            int r = wr*64 + fm*16 + lq*4 + rr;
            int c = wc*64 + fn*16 + lr;
            float v = (kg0 + c <= qg0 + r) ? acc[fm][fn][rr]*(1.f/32.f) : 0.f;
            float p = __expf(v - mS[fm][rr]) * lI[fm][rr];
            Ap[(size_t)r*S_ + kg0 + c] = p;
            Pt[r*128 + (((c>>3) + r)&15)*8 + (c&7)] = f2bf(p);
          }
      __syncthreads();
    } else {
      __syncthreads();
      int rt = tid >> 1, hk = tid & 1;
      float2 srow = stats[(size_t)bh*S_ + qt*128 + rt];
      float p = __expf(-srow.x) * (1.f / srow.y);
      unsigned short pb = f2bf(p);
      int rep = (unsigned)pb | ((unsigned)pb << 16);
      int4v pv = {rep, rep, rep, rep};
      float4 pf = {p, p, p, p};
      #pragma unroll
      for (int sl = 0; sl < 8; sl++){
        int slot = hk*8 + sl;
        *(int4v*)&Pt[rt*128 + ((slot + rt)&15)*8] = pv;
        *(float4*)&Ap[(size_t)rt*S_ + kt*128 + hk*64 + sl*8] = pf;
        *(float4*)&Ap[(size_t)rt*S_ + kt*128 + hk*64 + sl*8 + 4] = pf;
      }
      __syncthreads();
    }
    #pragma unroll
    for (int ks = 0; ks < 4; ks++){
      bf16x8 af[4], bfv[2];
      #pragma unroll
      for (int fm = 0; fm < 4; fm++){
        int r = wr*64 + fm*16 + lr;
        af[fm] = *(const bf16x8*)&Pt[r*128 + ((ks*4+lq + r)&15)*8];
      }
      #pragma unroll
      for (int fn = 0; fn < 2; fn++){
        int r = wc*32 + fn*16 + lr;
        bfv[fn] = *(const bf16x8*)&Vt[r*128 + ((ks*4+lq + r)&15)*8];
      }
      #pragma unroll
      for (int fm = 0; fm < 4; fm++)
        #pragma unroll
        for (int fn = 0; fn < 2; fn++)
          oacc[fm][fn] = __builtin_amdgcn_mfma_f32_16x16x32_bf16(af[fm], bfv[fn], oacc[fm][fn], 0, 0, 0);
    }
  }
  #pragma unroll
  for (int fm = 0; fm < 4; fm++)
    #pragma unroll
    for (int fn = 0; fn < 2; fn++){
      int d = wc*32 + fn*16 + lr;
      #pragma unroll
      for (int rr = 0; rr < 4; rr++){
        int q = qt*128 + wr*64 + fm*16 + lq*4 + rr;
        size_t orow = ((size_t)b*S_ + h*HD_ + (q>>4)) * D_ + ((q&15)<<6) + d;
        ctx[orow] = f2bf(oacc[fm][fn][rr]);
      }
    }
}

// ---- xcur = bf2f(lnb) + att ----
__global__ __launch_bounds__(256) void addbf(const unsigned short* __restrict__ a,
    const float* __restrict__ b, float* __restrict__ c){
  size_t i = ((size_t)blockIdx.x*256 + threadIdx.x)*4;
  ushort4 av = *(const ushort4*)&a[i];
  float4 bv = *(const float4*)&b[i];
  float4 o = {bf2f(av.x)+bv.x, bf2f(av.y)+bv.y, bf2f(av.z)+bv.z, bf2f(av.w)+bv.w};
  *(float4*)&c[i] = o;
}

// ============================================================================

extern "C" void kernel_launch(void* const* d_in, const int* in_sizes, int n_in,
                              void* d_out, int out_size, void* d_ws, size_t ws_size,
                              hipStream_t stream){
  const float* x0     = (const float*)d_in[0];
  const float* ln1_s  = (const float*)d_in[1];
  const float* ln1_b  = (const float*)d_in[2];
  const float* w_qkv1 = (const float*)d_in[3];
  const float* b_qkv1 = (const float*)d_in[4];
  const float* w_o1   = (const float*)d_in[5];
  const float* b_o1   = (const float*)d_in[6];
  const float* ln2_s  = (const float*)d_in[7];
  const float* ln2_b  = (const float*)d_in[8];
  const float* w_qkv2 = (const float*)d_in[9];
  const float* b_qkv2 = (const float*)d_in[10];
  const float* w_o2   = (const float*)d_in[11];
  const float* b_o2   = (const float*)d_in[12];
  const float* ln3_s  = (const float*)d_in[13];
  const float* ln3_b  = (const float*)d_in[14];
  const float* w1     = (const float*)d_in[15];
  const float* b1     = (const float*)d_in[16];
  const float* wg     = (const float*)d_in[17];
  const float* bg     = (const float*)d_in[18];
  const float* w2     = (const float*)d_in[19];
  const float* b2     = (const float*)d_in[20];

  const size_t MB_ = 1u<<20;
  if (ws_size < 148*MB_) return;   // harness provides >=148MB (verified)
  float* out_x = (float*)d_out;
  float* attn1 = out_x + 2*MB_;
  float* attn2 = attn1 + 32*MB_;
  dim3 blk(256);

  char* w8 = (char*)d_ws;
  float* att  = (float*)(w8 + 0);
  float* xcur = (float*)(w8 + 8*MB_);
  unsigned short* lnb     = (unsigned short*)(w8 + 16*MB_);
  unsigned short* wqkv1t  = (unsigned short*)(w8 + 20*MB_);
  unsigned short* wqkv2t  = (unsigned short*)(w8 + 26*MB_);
  unsigned short* wo1t    = (unsigned short*)(w8 + 32*MB_);
  unsigned short* wo2t    = (unsigned short*)(w8 + 34*MB_);
  unsigned short* w1t     = (unsigned short*)(w8 + 36*MB_);
  unsigned short* w2t     = (unsigned short*)(w8 + 44*MB_);
  unsigned short* wgt     = (unsigned short*)(w8 + 52*MB_);
  unsigned short* qhb     = (unsigned short*)(w8 + 116*MB_);
  unsigned short* khb     = (unsigned short*)(w8 + 120*MB_);
  unsigned short* vtb     = (unsigned short*)(w8 + 124*MB_);
  unsigned short* ctxb    = (unsigned short*)(w8 + 128*MB_);
  unsigned short* hbufb   = (unsigned short*)(w8 + 116*MB_);
  unsigned short* actb    = (unsigned short*)(w8 + 132*MB_);
  float2* stats           = (float2*)(w8 + 132*MB_);   // attention-phase only

  tcvt_all<<<49152, blk, 0, stream>>>(w_qkv1, w_qkv2, w_o1, w_o2, w1, wg, w2,
                                      wqkv1t, wqkv2t, wo1t, wo2t, w1t, wgt, w2t);
  // ---- layer 1 ----
  lnb_k<<<NROW_, blk, 0, stream>>>(x0, ln1_s, ln1_b, lnb);
  mqkv<<<dim3(24,16), blk, 0, stream>>>(lnb, wqkv1t, b_qkv1, qhb, khb, vtb);
  mstats<<<dim3(8,32), blk, 0, stream>>>(qhb, khb, stats);
  mpv<<<dim3(8,32), blk, 0, stream>>>(qhb, khb, vtb, stats, attn1, ctxb);
  mgemm64<true,true,false><<<dim3(16,16), blk, 0, stream>>>(ctxb, wo1t, b_o1, lnb, xcur, NROW_, D_, D_);
  // ---- layer 2 ----
  lnb_k<<<NROW_, blk, 0, stream>>>(xcur, ln2_s, ln2_b, lnb);
  mqkv<<<dim3(24,16), blk, 0, stream>>>(lnb, wqkv2t, b_qkv2, qhb, khb, vtb);
  mstats<<<dim3(8,32), blk, 0, stream>>>(qhb, khb, stats);
  mpv<<<dim3(8,32), blk, 0, stream>>>(qhb, khb, vtb, stats, attn2, ctxb);
  mgemm64<false,false,false><<<dim3(16,16), blk, 0, stream>>>(ctxb, wo2t, b_o2, nullptr, att, NROW_, D_, D_);
  addbf<<<2048, blk, 0, stream>>>(lnb, att, xcur);
  // ---- FFN ----
  lnb_k<<<NROW_, blk, 0, stream>>>(xcur, ln3_s, ln3_b, lnb);
  mgemm<false,false,true><<<dim3(32,16), blk, 0, stream>>>(lnb, w1t, b1, nullptr, hbufb, NROW_, FF_, D_);
  mgeglu<<<dim3(64,16), blk, 0, stream>>>(hbufb, wgt, bg, actb);
  mgemm64<true,false,false><<<dim3(16,16), blk, 0, stream>>>(actb, w2t, b2, att, out_x, NROW_, D_, FF_);
}